// Round 6
// baseline (541.217 us; speedup 1.0000x reference)
//
#include <hip/hip_runtime.h>
#include <hip/hip_bf16.h>

#define ALPHA 0.2f
// N=1024 particles, F_IN=6, NH=64, H=4 heads, T=12 steps.
// Key identity: attend values are LINEAR in the 6-dim input row, so every
// head-attend runs in 6-dim space: out_h = (Sum_j w * h_j) @ W_h; the 64-dim
// nonlinearity (ELU) is a per-row rank-1 pointwise afterwards.

__device__ __forceinline__ float wmax(float v){
  #pragma unroll
  for (int m = 1; m < 64; m <<= 1) v = fmaxf(v, __shfl_xor(v, m, 64));
  return v;
}

// Dtype detector: bf16 data never contains inf/NaN bit patterns (inputs finite);
// f32 data viewed as ushorts has ~0.78% such patterns. flag=1 -> f32; 0 -> bf16.
__global__ void k_detect(const unsigned short* __restrict__ s, int n, int* __restrict__ flag){
  int i = blockIdx.x * 256 + threadIdx.x;
  if (i < n){
    unsigned short u = s[i];
    if ((u & 0x7F80u) == 0x7F80u) atomicOr(flag, 1);
  }
}

// Merged conversion: states (73728 -> xs) + all 12 weight arrays (-> padded wsW).
struct Ptr13 { const void* p[13]; };
__global__ void k_cvtAll(Ptr13 src, float* __restrict__ xs, float* __restrict__ wsW,
                         const int* __restrict__ flag){
  const int n = blockIdx.x * 256 + threadIdx.x;
  const int F = *flag;
  if (n < 73728){
    xs[n] = F ? ((const float*)src.p[0])[n]
              : __bfloat162float(((const __hip_bfloat16*)src.p[0])[n]);
    return;
  }
  const int m = n - 73728;
  if (m >= 10788) return;
  const int segend[12] = {1536,2048,3584,3596,5132,5644,7180,7192,8728,9240,10776,10788};
  const int dstoff[12] = {0,1536,2048,3584,3600,5136,5648,7184,7200,8736,9248,10784};
  int seg = 0;
  #pragma unroll
  for (int i = 0; i < 12; ++i) if (m >= segend[i]) seg = i + 1;
  const int local = m - (seg ? segend[seg - 1] : 0);
  float v;
  if (F) v = ((const float*)src.p[seg + 1])[local];
  else   v = __bfloat162float(((const __hip_bfloat16*)src.p[seg + 1])[local]);
  wsW[dstoff[seg] + local] = v;
}

// Precompute Wa[L][h][sd][8] = W_heads @ a_heads halves (scores are linear in x:
// f_src(row) = x . (W @ a_src)); block 1 zeroes h_all[0] (initial state).
__global__ void k_prew(const float* __restrict__ wsW, float* __restrict__ WaG,
                       float* __restrict__ h0)
{
  if (blockIdx.x == 1){
    for (int i = threadIdx.x; i < 6144; i += 256) h0[i] = 0.f;
    return;
  }
  if (threadIdx.x < 144){
    const int d = threadIdx.x;
    const int L = d / 48, r2 = d % 48, h = r2 / 12, sd = (r2 % 12) / 6, f = r2 % 6;
    const int Woff[3] = {0, 3600, 7200};     // Wx, Wh, Wy
    const int aoff[3] = {1536, 5136, 8736};  // ax, ah, ay
    float s = 0.f;
    for (int k = 0; k < 64; ++k)
      s += wsW[Woff[L] + h * 384 + f * 64 + k] * wsW[aoff[L] + h * 128 + sd * 64 + k];
    WaG[((L * 4 + h) * 2 + sd) * 8 + f] = s;
  }
}

// A1: per-row 4-head GAT attend fully in 6-dim space + 64-dim pointwise.
// Per block: R rows (R = 256/LPR), all 4 heads, full j=1024.
//  - xS: input rows [1024][7] (stride 7 -> conflict-free for jg-strided reads)
//  - dT: dest scores [1024][5] per head slot (stride 5 -> conflict-free)
//  - attend: lane jg of a row accumulates acc6/den over j = jg + LPR*i
//  - pointwise: y6[r] = Sum_h ELU((acc6/den)@W_h)@Wout_h ; fs/fd = y6 . a_out
// Outputs: y6 ([t][1024][6]) + fsd ([t][2][1024]). No MFMA, no V buffers.
template<int LPR>
__launch_bounds__(256)
__global__ void k_gatA(const float* __restrict__ X, const float* __restrict__ Wa,
                       const float* __restrict__ W64, const float* __restrict__ Wout,
                       const float* __restrict__ aout,
                       float* __restrict__ y6out, float* __restrict__ fsdout)
{
  constexpr int R   = 256 / LPR;    // rows per block
  constexpr int LPP = 64 / R;       // lanes per (row,head) pair in pointwise
  constexpr int KPT = 64 / LPP;     // k-dims per thread in pointwise
  const int t  = threadIdx.x;
  const int tb = blockIdx.y;
  const int row0 = blockIdx.x * R;

  __shared__ float xS[1024 * 7];      // [j][7] (6 used)
  __shared__ float dT[1024 * 5];      // [j][5] slots: 4 heads + pad
  __shared__ float WS[1536];          // W64 [4][6][64]
  __shared__ float WoS[1536];         // Wout [256][6]
  __shared__ float WaS[64];           // [4][2][8]
  __shared__ float aoS[12];
  __shared__ float sS[4 * R];         // [h][r] row source scores
  __shared__ float maxdS[4];
  __shared__ float hS[R][4][8];       // {den, acc6}
  __shared__ float ypS[R][4][8];      // per-head y6 partials
  __shared__ float yS[R][6];

  const float* Xt = X + (size_t)tb * 6144;
  {
    const float4* x4 = (const float4*)Xt;
    for (int i = t; i < 1536; i += 256){
      float4 v = x4[i];
      const int base = i * 4;
      xS[(base    ) / 6 * 7 + (base    ) % 6] = v.x;
      xS[(base + 1) / 6 * 7 + (base + 1) % 6] = v.y;
      xS[(base + 2) / 6 * 7 + (base + 2) % 6] = v.z;
      xS[(base + 3) / 6 * 7 + (base + 3) % 6] = v.w;
    }
  }
  for (int i = t; i < 1536; i += 256){ WS[i] = W64[i]; WoS[i] = Wout[i]; }
  if (t < 64) WaS[t] = Wa[t];
  if (t < 12) aoS[t] = aout[t];
  __syncthreads();

  // dest scores for all 4 heads + source scores for this block's rows
  for (int p = t; p < 4096; p += 256){
    const int j = p >> 2, h = p & 3;
    const float* xr = &xS[j * 7];
    const float* wa = &WaS[(h * 2 + 1) * 8];
    float s = 0.f;
    #pragma unroll
    for (int f = 0; f < 6; ++f) s += xr[f] * wa[f];
    dT[j * 5 + h] = s;
  }
  if (t < 4 * R){
    const int r = t >> 2, h = t & 3;
    const float* xr = &xS[(row0 + r) * 7];
    const float* wa = &WaS[(h * 2) * 8];
    float s = 0.f;
    #pragma unroll
    for (int f = 0; f < 6; ++f) s += xr[f] * wa[f];
    sS[h * R + r] = s;
  }
  __syncthreads();
  {
    const int h = t >> 6, lane = t & 63;     // wave h reduces head h
    float lm = -1.0e30f;
    for (int j = lane; j < 1024; j += 64) lm = fmaxf(lm, dT[j * 5 + h]);
    lm = wmax(lm);
    if (lane == 0) maxdS[h] = lm;
  }
  __syncthreads();

  // 6-dim attend: row r handled by LPR lanes (jg), 4 heads serial
  const int r = t / LPR, jg = t % LPR;
  #pragma unroll
  for (int h = 0; h < 4; ++h){
    const float s = sS[h * R + r];
    float sm = s + maxdS[h];
    const float m = fmaxf(sm, ALPHA * sm);
    float acc[6] = {0.f,0.f,0.f,0.f,0.f,0.f};
    float den = 0.f;
    for (int j = jg; j < 1024; j += LPR){
      float e = s + dT[j * 5 + h]; e = fmaxf(e, ALPHA * e);
      const float w = __expf(fminf(e - m, 0.f));
      den += w;
      const float* xr = &xS[j * 7];
      #pragma unroll
      for (int f = 0; f < 6; ++f) acc[f] += w * xr[f];
    }
    #pragma unroll
    for (int mm = 1; mm < LPR; mm <<= 1){
      den += __shfl_xor(den, mm, 64);
      #pragma unroll
      for (int f = 0; f < 6; ++f) acc[f] += __shfl_xor(acc[f], mm, 64);
    }
    if (jg == 0){
      hS[r][h][0] = den;
      #pragma unroll
      for (int f = 0; f < 6; ++f) hS[r][h][1 + f] = acc[f];
    }
  }
  __syncthreads();

  // pointwise: pair p = (r,h), LPP lanes each cover KPT of 64 k-dims
  {
    const int p = t / LPP, kq = t % LPP;
    const int pr = p >> 2, ph = p & 3;
    const float inv = 1.f / hS[pr][ph][0];
    float hv[6];
    #pragma unroll
    for (int f = 0; f < 6; ++f) hv[f] = hS[pr][ph][1 + f] * inv;
    float yp[6] = {0.f,0.f,0.f,0.f,0.f,0.f};
    #pragma unroll
    for (int kk = 0; kk < KPT; ++kk){
      const int k = kq * KPT + kk;
      float o = 0.f;
      #pragma unroll
      for (int f = 0; f < 6; ++f) o += hv[f] * WS[ph * 384 + f * 64 + k];
      o = o > 0.f ? o : (__expf(o) - 1.f);           // ELU
      const float* wo = &WoS[(ph * 64 + k) * 6];
      #pragma unroll
      for (int f = 0; f < 6; ++f) yp[f] += o * wo[f];
    }
    #pragma unroll
    for (int mm = 1; mm < LPP; mm <<= 1)
      #pragma unroll
      for (int f = 0; f < 6; ++f) yp[f] += __shfl_xor(yp[f], mm, 64);
    if (kq == 0){
      #pragma unroll
      for (int f = 0; f < 6; ++f) ypS[pr][ph][f] = yp[f];
    }
  }
  __syncthreads();
  if (t < R * 6){
    const int rr = t / 6, f = t % 6;
    const float y = ypS[rr][0][f] + ypS[rr][1][f] + ypS[rr][2][f] + ypS[rr][3][f];
    yS[rr][f] = y;
    y6out[(size_t)tb * 6144 + (row0 + rr) * 6 + f] = y;
  }
  __syncthreads();
  if (t < 2 * R){
    const int rr = t >> 1, sd = t & 1;
    float s = 0.f;
    #pragma unroll
    for (int f = 0; f < 6; ++f) s += yS[rr][f] * aoS[sd * 6 + f];
    fsdout[(size_t)tb * 2048 + sd * 1024 + row0 + rr] = s;
  }
}

// A2: dense output attend (K=6) over y6 feats. 16 rows/block, grid (64, T).
// MODE 0: out = num/den -> f32out (Lx). MODE 1: f32out = addsrc + num/den (h_t).
// MODE 2: outv (dtype by flag) = addsrc + num/den (final y_t).
template<int MODE>
__launch_bounds__(256)
__global__ void k_gatB(const float* __restrict__ y6, const float* __restrict__ fsd,
                       const float* __restrict__ addsrc, float* __restrict__ f32out,
                       void* __restrict__ outv, const int* __restrict__ flag)
{
  const int tb = blockIdx.y;
  const int row0 = blockIdx.x * 16;
  const int t = threadIdx.x;
  const int wv = t >> 6, lane = t & 63;
  __shared__ __align__(16) float featS[6144];    // [1024][6] (stride-6 is conflict-free)
  __shared__ __align__(16) float dS[1024];
  __shared__ float sS[16];
  __shared__ float redW[4];

  const float* y6t = y6 + (size_t)tb * 6144;
  const float* ft  = fsd + (size_t)tb * 2048;
  {
    const float4* h4 = (const float4*)y6t;
    for (int i = t; i < 1536; i += 256) *(float4*)&featS[i * 4] = h4[i];
    if (t < 256) *(float4*)&dS[t * 4] = ((const float4*)(ft + 1024))[t];
    if (t < 16) sS[t] = ft[row0 + t];
  }
  __syncthreads();
  float lm = -1.0e30f;
  for (int i = t; i < 1024; i += 256) lm = fmaxf(lm, dS[i]);
  lm = wmax(lm);
  if (lane == 0) redW[wv] = lm;
  __syncthreads();
  const float maxd = fmaxf(fmaxf(redW[0], redW[1]), fmaxf(redW[2], redW[3]));

  const int r = t >> 4, jq = t & 15;
  const int row = row0 + r;
  const float s = sS[r];
  float m = s + maxd; m = fmaxf(m, ALPHA * m);
  float num[6] = {0.f,0.f,0.f,0.f,0.f,0.f};
  float den = 0.f;
  for (int j = jq; j < 1024; j += 16){
    float e = s + dS[j]; e = fmaxf(e, ALPHA * e);
    const float w = __expf(fminf(e - m, 0.f));
    den += w;
    const float* fr = &featS[j * 6];
    #pragma unroll
    for (int f = 0; f < 6; ++f) num[f] += w * fr[f];
  }
  #pragma unroll
  for (int mm = 1; mm < 16; mm <<= 1){
    den += __shfl_xor(den, mm, 64);
    #pragma unroll
    for (int f = 0; f < 6; ++f) num[f] += __shfl_xor(num[f], mm, 64);
  }
  if (jq == 0){
    const float inv = 1.f / den;
    if (MODE == 0){
      float* dst = f32out + (size_t)tb * 6144 + row * 6;
      #pragma unroll
      for (int f = 0; f < 6; ++f) dst[f] = num[f] * inv;
    } else if (MODE == 1){
      const float* a = addsrc + row * 6;
      float* dst = f32out + row * 6;
      #pragma unroll
      for (int f = 0; f < 6; ++f) dst[f] = a[f] + num[f] * inv;
    } else {
      const float* a = addsrc + (size_t)tb * 6144 + row * 6;
      const int base = tb * 6144 + row * 6;
      if (*flag){
        float* dst = (float*)outv;
        #pragma unroll
        for (int f = 0; f < 6; ++f) dst[base + f] = a[f] + num[f] * inv;
      } else {
        __hip_bfloat16* dst = (__hip_bfloat16*)outv;
        #pragma unroll
        for (int f = 0; f < 6; ++f) dst[base + f] = __float2bfloat16(a[f] + num[f] * inv);
      }
    }
  }
}

extern "C" void kernel_launch(void* const* d_in, const int* in_sizes, int n_in,
                              void* d_out, int out_size, void* d_ws, size_t ws_size,
                              hipStream_t stream) {
  (void)in_sizes; (void)n_in; (void)out_size;

  const size_t avail = ws_size / 4;
  if (avail < 340000u) return;   // ~1.4 MB needed

  float* ws = (float*)d_ws;
  size_t off = 0;
  int*   flag  = (int*)(ws + off); off += 16;
  float* xs    = ws + off; off += 73728;
  float* wsW   = ws + off; off += 10800;
  float* Lx    = ws + off; off += 73728;
  float* WaG   = ws + off; off += 256;
  float* h_all = ws + off; off += 79872;    // [13][1024][6]; [0] = zeros
  float* y6a   = ws + off; off += 73728;    // [12][1024][6]
  float* fsdA  = ws + off; off += 24576;    // [12][2][1024]

  hipMemsetAsync(flag, 0, 4, stream);
  k_detect<<<288, 256, 0, stream>>>((const unsigned short*)d_in[0], 73728, flag);
  Ptr13 ptrs;
  for (int i = 0; i < 13; ++i) ptrs.p[i] = d_in[i];
  k_cvtAll<<<331, 256, 0, stream>>>(ptrs, xs, wsW, flag);
  k_prew<<<2, 256, 0, stream>>>(wsW, WaG, h_all);

  float *Wx = wsW, *Wxo = wsW + 2048, *axo = wsW + 3584;
  float *Wh = wsW + 3600, *Who = wsW + 5648, *aho = wsW + 7184;
  float *Wy = wsW + 7200, *Wyo = wsW + 9248, *ayo = wsW + 10784;

  // Phase 1 (batched over t): Lx[t] = pat_layer(x_t, Wx, ax, Wxo, axo)
  k_gatA<16><<<dim3(64, 12), 256, 0, stream>>>(xs, WaG, Wx, Wxo, axo, y6a, fsdA);
  k_gatB<0><<<dim3(64, 12), 256, 0, stream>>>(y6a, fsdA, nullptr, Lx, nullptr, flag);

  // Phase 2 (sequential recurrence): h_t = Lx_t + pat_layer(h_{t-1}, Wh...)
  for (int t = 0; t < 12; ++t){
    k_gatA<64><<<dim3(256, 1), 256, 0, stream>>>(h_all + (size_t)t * 6144, WaG + 64,
                                                 Wh, Who, aho, y6a, fsdA);
    k_gatB<1><<<dim3(64, 1), 256, 0, stream>>>(y6a, fsdA, Lx + (size_t)t * 6144,
                                               h_all + (size_t)(t + 1) * 6144,
                                               nullptr, flag);
  }

  // Phase 3 (batched over t): y_t = x_t + pat_layer(h_t, Wy, ay, Wyo, ayo)
  k_gatA<16><<<dim3(64, 12), 256, 0, stream>>>(h_all + 6144, WaG + 128, Wy, Wyo, ayo,
                                               y6a, fsdA);
  k_gatB<2><<<dim3(64, 12), 256, 0, stream>>>(y6a, fsdA, xs, nullptr, d_out, flag);
}